// Round 5
// baseline (680.541 us; speedup 1.0000x reference)
//
#include <hip/hip_runtime.h>

typedef _Float16 half8 __attribute__((ext_vector_type(8)));
typedef _Float16 half4 __attribute__((ext_vector_type(4)));
typedef float    floatx4 __attribute__((ext_vector_type(4)));

#define NB  16
#define SEQ 2048
#define DIM 64

#define MFMA32(a,b,c) __builtin_amdgcn_mfma_f32_16x16x32_f16((a),(b),(c),0,0,0)
#define MFMA16(a,b,c) __builtin_amdgcn_mfma_f32_16x16x16f16((a),(b),(c),0,0,0)

// ---- pre-pass: q,k fp32 -> f16 (straight copy-convert) ----
__global__ __launch_bounds__(256) void cvt_qk_kernel(const float* __restrict__ q,
                                                     const float* __restrict__ k,
                                                     _Float16* __restrict__ qh,
                                                     _Float16* __restrict__ kh) {
    size_t i = ((size_t)blockIdx.x * 256 + threadIdx.x) * 4;
    float4 a = *(const float4*)(q + i);
    float4 b = *(const float4*)(k + i);
    half4 ha = { (_Float16)a.x, (_Float16)a.y, (_Float16)a.z, (_Float16)a.w };
    half4 hb = { (_Float16)b.x, (_Float16)b.y, (_Float16)b.z, (_Float16)b.w };
    *(half4*)(qh + i) = ha;
    *(half4*)(kh + i) = hb;
}

// ---- pre-pass: v [B][S][D] fp32 -> vt [B][D][S] f16 (LDS tile transpose) ----
__global__ __launch_bounds__(256) void cvt_vt_kernel(const float* __restrict__ v,
                                                     _Float16* __restrict__ vt) {
    __shared__ float tile[64][65];
    const int b  = blockIdx.x >> 5;
    const int s0 = (blockIdx.x & 31) << 6;
    const int t  = threadIdx.x;
    {
        const int row = t >> 2;            // s-local 0..63
        const int c0  = (t & 3) << 4;      // d base
        const float* src = v + ((size_t)(b * SEQ + s0 + row)) * DIM + c0;
        #pragma unroll
        for (int i = 0; i < 4; ++i) {
            float4 x = *(const float4*)(src + i * 4);
            tile[row][c0 + i*4 + 0] = x.x;
            tile[row][c0 + i*4 + 1] = x.y;
            tile[row][c0 + i*4 + 2] = x.z;
            tile[row][c0 + i*4 + 3] = x.w;
        }
    }
    __syncthreads();
    {
        const int d  = t >> 2;             // 0..63
        const int sb = (t & 3) << 4;       // s-local base
        _Float16* dst = vt + ((size_t)(b * DIM + d)) * SEQ + s0 + sb;
        #pragma unroll
        for (int i = 0; i < 4; ++i) {
            half4 h = { (_Float16)tile[sb + i*4 + 0][d],
                        (_Float16)tile[sb + i*4 + 1][d],
                        (_Float16)tile[sb + i*4 + 2][d],
                        (_Float16)tile[sb + i*4 + 3][d] };
            *(half4*)(dst + i*4) = h;
        }
    }
}

// ---- pre-pass: mask int32 -> 1 bit/elem via ballot ----
// ILP fix: all 32 loads issue first (independent), ballots run on registers.
__global__ __launch_bounds__(256) void mask_bits_kernel(const int* __restrict__ mask,
                                                        unsigned int* __restrict__ bits) {
    const int wave = threadIdx.x >> 6;
    const int lane = threadIdx.x & 63;
    const size_t row = (size_t)blockIdx.x * 4 + wave;   // 16*2048 rows total
    const int* mp = mask + row * SEQ + lane;
    int m[32];
    #pragma unroll
    for (int it = 0; it < 32; ++it)
        m[it] = __builtin_nontemporal_load(mp + it * 64);
    unsigned int keep = 0;
    #pragma unroll
    for (int it = 0; it < 32; ++it) {
        unsigned long long bal = __ballot(m[it] != 0);
        unsigned int half = (lane & 1) ? (unsigned int)(bal >> 32) : (unsigned int)bal;
        if ((lane >> 1) == it) keep = half;
    }
    bits[row * 64 + lane] = keep;
}

// ---- fused attention: one block = 16 q-rows of one b ----
// Pass A: swapped QK^T -> exp -> rowsum, one-deep K prefetch.
// Pass B: recompute QK, emit normalized fp32 attn, PV directly off the QK
//   output with K=16 MFMAs (swapped-QK C-layout == MFMA16 B-fragment).
// CRITICAL ORDERING: loads and stores share vmcnt. All loads consumed by an
// iteration are issued one iteration EARLY (before that iteration's stores),
// so every in-loop s_waitcnt targets OLD loads (vmcnt(N), N>0) and the attn
// stores are never drained inside the loop -> stores complete asynchronously.
// Wrapped prefetch indices (&2047) avoid guard branches (last prefetch is a
// harmless dummy re-read of the block's own data).
// XCD-chunk swizzle pins each XCD to 2 batches -> K/V/Q/bits L2-resident.
__global__ __launch_bounds__(256, 4) void attn_kernel(
    const _Float16* __restrict__ qh, const _Float16* __restrict__ kh,
    const _Float16* __restrict__ vt, const unsigned int* __restrict__ bits,
    float* __restrict__ out, float* __restrict__ attn)
{
    __shared__ float wsum[4][16];
    __shared__ __align__(16) float outred[4][16][68];   // cross-wave out reduction

    // bijective XCD swizzle: 2048 blocks, 8 XCDs, 256 contiguous per XCD
    const int blk  = ((blockIdx.x & 7) << 8) + (blockIdx.x >> 3);
    const int b    = blk >> 7;
    const int r0   = (blk & 127) << 4;
    const int lane = threadIdx.x & 63;
    const int wave = threadIdx.x >> 6;
    const int rl   = lane & 15;   // q-row (MFMA n-index)
    const int g    = lane >> 4;   // quad

    // Q fragment (B-operand of swapped QK): Q[r0+rl][g*8..+7], both K=32 halves
    const size_t qoff = ((size_t)(b * SEQ + r0 + rl)) * DIM + g * 8;
    const half8 qa0 = *(const half8*)(qh + qoff);
    const half8 qa1 = *(const half8*)(qh + qoff + 32);

    const _Float16* kbase = kh + (size_t)b * SEQ * DIM + (size_t)rl * DIM + g * 8;
    const _Float16* vbase = vt + ((size_t)b * DIM + rl) * SEQ + g * 4;
    const unsigned int* bbase = bits + ((size_t)(b * SEQ + r0 + rl)) * 64 + wave;

    // ---------------- pass A: QK -> exp -> rowsum (K prefetched 1 deep) ----------------
    float rs = 0.f;
    unsigned int pb = bbase[0];
    {
        const _Float16* kp = kbase + (size_t)(wave * 32) * DIM;
        half8 ka0 = *(const half8*)(kp);
        half8 ka1 = *(const half8*)(kp + 32);
        half8 kb0 = *(const half8*)(kp + 16 * DIM);
        half8 kb1 = *(const half8*)(kp + 16 * DIM + 32);

        for (int cc = 0; cc < 16; ++cc) {
            // prefetch next chunk (wrapped at cc=15: harmless dummy)
            const int jn = (((cc + 1) * 4 + wave) * 32) & (SEQ - 1);
            const _Float16* kn = kbase + (size_t)jn * DIM;
            half8 na0 = *(const half8*)(kn);
            half8 na1 = *(const half8*)(kn + 32);
            half8 nb0 = *(const half8*)(kn + 16 * DIM);
            half8 nb1 = *(const half8*)(kn + 16 * DIM + 32);
            const unsigned int bm = pb;
            pb = bbase[((cc + 1) * 4) & 63];

            floatx4 c0 = {0.f,0.f,0.f,0.f}, c1 = {0.f,0.f,0.f,0.f};
            c0 = MFMA32(ka0, qa0, c0);
            c0 = MFMA32(ka1, qa1, c0);
            c1 = MFMA32(kb0, qa0, c1);
            c1 = MFMA32(kb1, qa1, c1);
            const unsigned int blo = bm >> (g * 4);
            const unsigned int bhi = bm >> (g * 4 + 16);
            float e0 = (blo & 1u) ? 0.f : __expf(c0[0] * 0.125f);
            float e1 = (blo & 2u) ? 0.f : __expf(c0[1] * 0.125f);
            float e2 = (blo & 4u) ? 0.f : __expf(c0[2] * 0.125f);
            float e3 = (blo & 8u) ? 0.f : __expf(c0[3] * 0.125f);
            float e4 = (bhi & 1u) ? 0.f : __expf(c1[0] * 0.125f);
            float e5 = (bhi & 2u) ? 0.f : __expf(c1[1] * 0.125f);
            float e6 = (bhi & 4u) ? 0.f : __expf(c1[2] * 0.125f);
            float e7 = (bhi & 8u) ? 0.f : __expf(c1[3] * 0.125f);
            rs += (e0 + e1) + (e2 + e3) + (e4 + e5) + (e6 + e7);

            ka0 = na0; ka1 = na1; kb0 = nb0; kb1 = nb1;
        }
    }

    // row-sum: the 4 lanes sharing rl are {l, l^16, l^32, l^48}
    rs += __shfl_xor(rs, 16);
    rs += __shfl_xor(rs, 32);
    if (g == 0) wsum[wave][rl] = rs;
    __syncthreads();
    const float inv = 1.0f / (wsum[0][rl] + wsum[1][rl] + wsum[2][rl] + wsum[3][rl]);

    // ------- pass B: recompute QK, emit attn, PV via direct MFMA16 -------
    // K, V, bits all prefetched one iteration ahead of the stores.
    floatx4 o0 = {0.f,0.f,0.f,0.f}, o1 = {0.f,0.f,0.f,0.f};
    floatx4 o2 = {0.f,0.f,0.f,0.f}, o3 = {0.f,0.f,0.f,0.f};
    float* abase = attn + ((size_t)(b * SEQ + r0 + rl)) * SEQ + g * 4;

    {
        const _Float16* kp = kbase + (size_t)(wave * 32) * DIM;
        half8 ka0 = *(const half8*)(kp);
        half8 ka1 = *(const half8*)(kp + 32);
        half8 kb0 = *(const half8*)(kp + 16 * DIM);
        half8 kb1 = *(const half8*)(kp + 16 * DIM + 32);
        const _Float16* vp = vbase + wave * 32;
        half4 va00 = *(const half4*)(vp);
        half4 va01 = *(const half4*)(vp + 16);
        half4 va10 = *(const half4*)(vp + 16 * SEQ);
        half4 va11 = *(const half4*)(vp + 16 * SEQ + 16);
        half4 va20 = *(const half4*)(vp + 32 * SEQ);
        half4 va21 = *(const half4*)(vp + 32 * SEQ + 16);
        half4 va30 = *(const half4*)(vp + 48 * SEQ);
        half4 va31 = *(const half4*)(vp + 48 * SEQ + 16);
        unsigned int bm = bbase[0];

        for (int cc = 0; cc < 16; ++cc) {
            const int jj = (cc * 4 + wave) * 32;
            // ---- prefetch next iteration (before any store this iteration) ----
            const int jn = (((cc + 1) * 4 + wave) * 32) & (SEQ - 1);
            const _Float16* kn = kbase + (size_t)jn * DIM;
            half8 na0 = *(const half8*)(kn);
            half8 na1 = *(const half8*)(kn + 32);
            half8 nb0 = *(const half8*)(kn + 16 * DIM);
            half8 nb1 = *(const half8*)(kn + 16 * DIM + 32);
            const _Float16* vn = vbase + jn;
            half4 wa00 = *(const half4*)(vn);
            half4 wa01 = *(const half4*)(vn + 16);
            half4 wa10 = *(const half4*)(vn + 16 * SEQ);
            half4 wa11 = *(const half4*)(vn + 16 * SEQ + 16);
            half4 wa20 = *(const half4*)(vn + 32 * SEQ);
            half4 wa21 = *(const half4*)(vn + 32 * SEQ + 16);
            half4 wa30 = *(const half4*)(vn + 48 * SEQ);
            half4 wa31 = *(const half4*)(vn + 48 * SEQ + 16);
            const unsigned int bmn = bbase[((cc + 1) * 4) & 63];

            // ---- compute on current (waits target OLD loads only) ----
            floatx4 c0 = {0.f,0.f,0.f,0.f}, c1 = {0.f,0.f,0.f,0.f};
            c0 = MFMA32(ka0, qa0, c0);
            c0 = MFMA32(ka1, qa1, c0);
            c1 = MFMA32(kb0, qa0, c1);
            c1 = MFMA32(kb1, qa1, c1);

            const unsigned int blo = bm >> (g * 4);
            const unsigned int bhi = bm >> (g * 4 + 16);
            float e0 = (blo & 1u) ? 0.f : __expf(c0[0] * 0.125f);
            float e1 = (blo & 2u) ? 0.f : __expf(c0[1] * 0.125f);
            float e2 = (blo & 4u) ? 0.f : __expf(c0[2] * 0.125f);
            float e3 = (blo & 8u) ? 0.f : __expf(c0[3] * 0.125f);
            float e4 = (bhi & 1u) ? 0.f : __expf(c1[0] * 0.125f);
            float e5 = (bhi & 2u) ? 0.f : __expf(c1[1] * 0.125f);
            float e6 = (bhi & 4u) ? 0.f : __expf(c1[2] * 0.125f);
            float e7 = (bhi & 8u) ? 0.f : __expf(c1[3] * 0.125f);

            // e packed f16 == PV B-fragment directly (K=16 MFMA)
            half4 h0 = { (_Float16)e0, (_Float16)e1, (_Float16)e2, (_Float16)e3 };
            half4 h1 = { (_Float16)e4, (_Float16)e5, (_Float16)e6, (_Float16)e7 };
            o0 = MFMA16(va00, h0, o0);
            o0 = MFMA16(va01, h1, o0);
            o1 = MFMA16(va10, h0, o1);
            o1 = MFMA16(va11, h1, o1);
            o2 = MFMA16(va20, h0, o2);
            o2 = MFMA16(va21, h1, o2);
            o3 = MFMA16(va30, h0, o3);
            o3 = MFMA16(va31, h1, o3);

            // ---- stores LAST: never waited on inside the loop ----
            floatx4 a0 = { e0 * inv, e1 * inv, e2 * inv, e3 * inv };
            floatx4 a1 = { e4 * inv, e5 * inv, e6 * inv, e7 * inv };
            *(floatx4*)(abase + jj)      = a0;
            *(floatx4*)(abase + jj + 16) = a1;

            ka0 = na0; ka1 = na1; kb0 = nb0; kb1 = nb1;
            va00 = wa00; va01 = wa01; va10 = wa10; va11 = wa11;
            va20 = wa20; va21 = wa21; va30 = wa30; va31 = wa31;
            bm = bmn;
        }
    }

    // ---- cross-wave reduction of out partials ----
    // o{dt}[i] = out[rl][dt*16 + g*4 + i] (this wave's j-chunks only, unnormalized)
    {
        float* orow = &outred[wave][rl][g * 4];
        *(floatx4*)(orow +  0) = o0;
        *(floatx4*)(orow + 16) = o1;
        *(floatx4*)(orow + 32) = o2;
        *(floatx4*)(orow + 48) = o3;
    }
    __syncthreads();
    {
        const int r  = threadIdx.x >> 4;        // 0..15
        const int c4 = (threadIdx.x & 15) << 2; // 0,4,..,60
        floatx4 s0 = *(const floatx4*)(&outred[0][r][c4]);
        floatx4 s1 = *(const floatx4*)(&outred[1][r][c4]);
        floatx4 s2 = *(const floatx4*)(&outred[2][r][c4]);
        floatx4 s3 = *(const floatx4*)(&outred[3][r][c4]);
        floatx4 s = (s0 + s1) + (s2 + s3);
        const float inv2 = 1.0f / (wsum[0][r] + wsum[1][r] + wsum[2][r] + wsum[3][r]);
        floatx4 ov = { s[0] * inv2, s[1] * inv2, s[2] * inv2, s[3] * inv2 };
        *(floatx4*)(out + ((size_t)(b * SEQ + r0 + r)) * DIM + c4) = ov;
    }
}

extern "C" void kernel_launch(void* const* d_in, const int* in_sizes, int n_in,
                              void* d_out, int out_size, void* d_ws, size_t ws_size,
                              hipStream_t stream) {
    const float* q = (const float*)d_in[0];
    const float* k = (const float*)d_in[1];
    const float* v = (const float*)d_in[2];
    const int* mask = (const int*)d_in[3];   // bool delivered as int32 per harness

    float* out  = (float*)d_out;                       // [16,2048,64]
    float* attn = out + (size_t)NB * SEQ * DIM;        // [16,2048,2048]

    // workspace: qh | kh | vt (f16, 4 MB each) | bits (8 MB) = 20 MB total
    _Float16* qh = (_Float16*)d_ws;
    _Float16* kh = qh + (size_t)NB * SEQ * DIM;
    _Float16* vt = kh + (size_t)NB * SEQ * DIM;
    unsigned int* bits = (unsigned int*)(vt + (size_t)NB * SEQ * DIM);

    cvt_qk_kernel<<<(NB * SEQ * DIM) / 1024, 256, 0, stream>>>(q, k, qh, kh);
    cvt_vt_kernel<<<NB * (SEQ / 64), 256, 0, stream>>>(v, vt);
    mask_bits_kernel<<<(NB * SEQ) / 4, 256, 0, stream>>>(mask, bits);
    attn_kernel<<<NB * (SEQ / 16), 256, 0, stream>>>(qh, kh, vt, bits, out, attn);
}

// Round 6
// 666.861 us; speedup vs baseline: 1.0205x; 1.0205x over previous
//
#include <hip/hip_runtime.h>

typedef _Float16 half8 __attribute__((ext_vector_type(8)));
typedef _Float16 half4 __attribute__((ext_vector_type(4)));
typedef float    floatx4 __attribute__((ext_vector_type(4)));

#define NB  16
#define SEQ 2048
#define DIM 64

#define MFMA32(a,b,c) __builtin_amdgcn_mfma_f32_16x16x32_f16((a),(b),(c),0,0,0)
#define MFMA16(a,b,c) __builtin_amdgcn_mfma_f32_16x16x16f16((a),(b),(c),0,0,0)

// ---- pre-pass: q,k fp32 -> f16 (straight copy-convert) ----
__global__ __launch_bounds__(256) void cvt_qk_kernel(const float* __restrict__ q,
                                                     const float* __restrict__ k,
                                                     _Float16* __restrict__ qh,
                                                     _Float16* __restrict__ kh) {
    size_t i = ((size_t)blockIdx.x * 256 + threadIdx.x) * 4;
    float4 a = *(const float4*)(q + i);
    float4 b = *(const float4*)(k + i);
    half4 ha = { (_Float16)a.x, (_Float16)a.y, (_Float16)a.z, (_Float16)a.w };
    half4 hb = { (_Float16)b.x, (_Float16)b.y, (_Float16)b.z, (_Float16)b.w };
    *(half4*)(qh + i) = ha;
    *(half4*)(kh + i) = hb;
}

// ---- pre-pass: v [B][S][D] fp32 -> vt [B][D][S] f16 (LDS tile transpose) ----
__global__ __launch_bounds__(256) void cvt_vt_kernel(const float* __restrict__ v,
                                                     _Float16* __restrict__ vt) {
    __shared__ float tile[64][65];
    const int b  = blockIdx.x >> 5;
    const int s0 = (blockIdx.x & 31) << 6;
    const int t  = threadIdx.x;
    {
        const int row = t >> 2;            // s-local 0..63
        const int c0  = (t & 3) << 4;      // d base
        const float* src = v + ((size_t)(b * SEQ + s0 + row)) * DIM + c0;
        #pragma unroll
        for (int i = 0; i < 4; ++i) {
            float4 x = *(const float4*)(src + i * 4);
            tile[row][c0 + i*4 + 0] = x.x;
            tile[row][c0 + i*4 + 1] = x.y;
            tile[row][c0 + i*4 + 2] = x.z;
            tile[row][c0 + i*4 + 3] = x.w;
        }
    }
    __syncthreads();
    {
        const int d  = t >> 2;             // 0..63
        const int sb = (t & 3) << 4;       // s-local base
        _Float16* dst = vt + ((size_t)(b * DIM + d)) * SEQ + s0 + sb;
        #pragma unroll
        for (int i = 0; i < 4; ++i) {
            half4 h = { (_Float16)tile[sb + i*4 + 0][d],
                        (_Float16)tile[sb + i*4 + 1][d],
                        (_Float16)tile[sb + i*4 + 2][d],
                        (_Float16)tile[sb + i*4 + 3][d] };
            *(half4*)(dst + i*4) = h;
        }
    }
}

// ---- pre-pass: mask int32 -> 1 bit/elem via ballot ----
// All 32 loads issue first (independent), ballots run on registers.
__global__ __launch_bounds__(256) void mask_bits_kernel(const int* __restrict__ mask,
                                                        unsigned int* __restrict__ bits) {
    const int wave = threadIdx.x >> 6;
    const int lane = threadIdx.x & 63;
    const size_t row = (size_t)blockIdx.x * 4 + wave;   // 16*2048 rows total
    const int* mp = mask + row * SEQ + lane;
    int m[32];
    #pragma unroll
    for (int it = 0; it < 32; ++it)
        m[it] = __builtin_nontemporal_load(mp + it * 64);
    unsigned int keep = 0;
    #pragma unroll
    for (int it = 0; it < 32; ++it) {
        unsigned long long bal = __ballot(m[it] != 0);
        unsigned int half = (lane & 1) ? (unsigned int)(bal >> 32) : (unsigned int)bal;
        if ((lane >> 1) == it) keep = half;
    }
    bits[row * 64 + lane] = keep;
}

// ---- fused attention: one block = 16 q-rows of one b ----
// Base = round-2 empirical best (228us). Two contained changes:
//  * pass A: unroll-2 over column chunks -> 8 independent K-loads in flight
//    per wave (double MLP), two independent MFMA->exp chains per iteration.
//  * pass B: PV runs DIRECTLY off the QK output via K=16 MFMAs (the
//    swapped-QK C-layout lane(rl,g) reg i = e[rl][jj+g*4+i] is exactly the
//    mfma_16x16x16 B-fragment) -- removes the ds_write->ds_read lgkmcnt
//    stall of the LDS bounce. NO XCD swizzle (r3/r4 regression suspect).
__global__ __launch_bounds__(256, 6) void attn_kernel(
    const _Float16* __restrict__ qh, const _Float16* __restrict__ kh,
    const _Float16* __restrict__ vt, const unsigned int* __restrict__ bits,
    float* __restrict__ out, float* __restrict__ attn)
{
    __shared__ float wsum[4][16];
    __shared__ __align__(16) float outred[4][16][68];   // cross-wave out reduction

    const int b    = blockIdx.x >> 7;
    const int r0   = (blockIdx.x & 127) << 4;
    const int lane = threadIdx.x & 63;
    const int wave = threadIdx.x >> 6;
    const int rl   = lane & 15;   // q-row (MFMA n-index)
    const int g    = lane >> 4;   // quad

    // Q fragment (B-operand of swapped QK): Q[r0+rl][g*8..+7], both K=32 halves
    const size_t qoff = ((size_t)(b * SEQ + r0 + rl)) * DIM + g * 8;
    const half8 qa0 = *(const half8*)(qh + qoff);
    const half8 qa1 = *(const half8*)(qh + qoff + 32);

    const _Float16* kbase = kh + (size_t)b * SEQ * DIM + (size_t)rl * DIM + g * 8;
    const _Float16* vbase = vt + ((size_t)b * DIM + rl) * SEQ + g * 4;
    const unsigned int* bbase = bits + ((size_t)(b * SEQ + r0 + rl)) * 64 + wave;

    // -------- pass A (lean, unroll-2): QK -> exp -> rowsum --------
    float rs = 0.f;

    for (int cc = 0; cc < 16; cc += 2) {
        const int jA = ((cc    ) * 4 + wave) * 32;
        const int jB = ((cc + 1) * 4 + wave) * 32;
        const unsigned int bmA = bbase[cc * 4];
        const unsigned int bmB = bbase[cc * 4 + 4];
        const _Float16* kpA = kbase + (size_t)jA * DIM;
        const _Float16* kpB = kbase + (size_t)jB * DIM;
        // chunk A loads
        half8 ka0 = *(const half8*)(kpA);
        half8 ka1 = *(const half8*)(kpA + 32);
        half8 ka2 = *(const half8*)(kpA + 16 * DIM);
        half8 ka3 = *(const half8*)(kpA + 16 * DIM + 32);
        // chunk B loads (independent)
        half8 kb0 = *(const half8*)(kpB);
        half8 kb1 = *(const half8*)(kpB + 32);
        half8 kb2 = *(const half8*)(kpB + 16 * DIM);
        half8 kb3 = *(const half8*)(kpB + 16 * DIM + 32);

        floatx4 cA0 = {0.f,0.f,0.f,0.f}, cA1 = {0.f,0.f,0.f,0.f};
        floatx4 cB0 = {0.f,0.f,0.f,0.f}, cB1 = {0.f,0.f,0.f,0.f};
        cA0 = MFMA32(ka0, qa0, cA0);
        cA0 = MFMA32(ka1, qa1, cA0);
        cA1 = MFMA32(ka2, qa0, cA1);
        cA1 = MFMA32(ka3, qa1, cA1);
        cB0 = MFMA32(kb0, qa0, cB0);
        cB0 = MFMA32(kb1, qa1, cB0);
        cB1 = MFMA32(kb2, qa0, cB1);
        cB1 = MFMA32(kb3, qa1, cB1);

        const unsigned int aLo = bmA >> (g * 4);
        const unsigned int aHi = bmA >> (g * 4 + 16);
        const unsigned int bLo = bmB >> (g * 4);
        const unsigned int bHi = bmB >> (g * 4 + 16);
        float e0 = (aLo & 1u) ? 0.f : __expf(cA0[0] * 0.125f);
        float e1 = (aLo & 2u) ? 0.f : __expf(cA0[1] * 0.125f);
        float e2 = (aLo & 4u) ? 0.f : __expf(cA0[2] * 0.125f);
        float e3 = (aLo & 8u) ? 0.f : __expf(cA0[3] * 0.125f);
        float e4 = (aHi & 1u) ? 0.f : __expf(cA1[0] * 0.125f);
        float e5 = (aHi & 2u) ? 0.f : __expf(cA1[1] * 0.125f);
        float e6 = (aHi & 4u) ? 0.f : __expf(cA1[2] * 0.125f);
        float e7 = (aHi & 8u) ? 0.f : __expf(cA1[3] * 0.125f);
        float f0 = (bLo & 1u) ? 0.f : __expf(cB0[0] * 0.125f);
        float f1 = (bLo & 2u) ? 0.f : __expf(cB0[1] * 0.125f);
        float f2 = (bLo & 4u) ? 0.f : __expf(cB0[2] * 0.125f);
        float f3 = (bLo & 8u) ? 0.f : __expf(cB0[3] * 0.125f);
        float f4 = (bHi & 1u) ? 0.f : __expf(cB1[0] * 0.125f);
        float f5 = (bHi & 2u) ? 0.f : __expf(cB1[1] * 0.125f);
        float f6 = (bHi & 4u) ? 0.f : __expf(cB1[2] * 0.125f);
        float f7 = (bHi & 8u) ? 0.f : __expf(cB1[3] * 0.125f);
        rs += ((e0 + e1) + (e2 + e3)) + ((e4 + e5) + (e6 + e7))
            + ((f0 + f1) + (f2 + f3)) + ((f4 + f5) + (f6 + f7));
    }

    // row-sum: the 4 lanes sharing rl are {l, l^16, l^32, l^48}
    rs += __shfl_xor(rs, 16);
    rs += __shfl_xor(rs, 32);
    if (g == 0) wsum[wave][rl] = rs;
    __syncthreads();
    const float inv = 1.0f / (wsum[0][rl] + wsum[1][rl] + wsum[2][rl] + wsum[3][rl]);

    // ------- pass B: recompute QK, emit attn, PV via direct MFMA16 -------
    floatx4 o0 = {0.f,0.f,0.f,0.f}, o1 = {0.f,0.f,0.f,0.f};
    floatx4 o2 = {0.f,0.f,0.f,0.f}, o3 = {0.f,0.f,0.f,0.f};
    float* abase = attn + ((size_t)(b * SEQ + r0 + rl)) * SEQ + g * 4;

    for (int cc = 0; cc < 16; ++cc) {
        const int jj = (cc * 4 + wave) * 32;
        const unsigned int bm = bbase[cc * 4];     // L1-hot after pass A
        const _Float16* kp = kbase + (size_t)jj * DIM;
        half8 ka0 = *(const half8*)(kp);
        half8 ka1 = *(const half8*)(kp + 32);
        half8 kb0 = *(const half8*)(kp + 16 * DIM);
        half8 kb1 = *(const half8*)(kp + 16 * DIM + 32);
        // V loads issue up front with K (13 loads in flight)
        const _Float16* vp = vbase + jj;
        half4 va00 = *(const half4*)(vp);
        half4 va01 = *(const half4*)(vp + 16);
        half4 va10 = *(const half4*)(vp + 16 * SEQ);
        half4 va11 = *(const half4*)(vp + 16 * SEQ + 16);
        half4 va20 = *(const half4*)(vp + 32 * SEQ);
        half4 va21 = *(const half4*)(vp + 32 * SEQ + 16);
        half4 va30 = *(const half4*)(vp + 48 * SEQ);
        half4 va31 = *(const half4*)(vp + 48 * SEQ + 16);

        floatx4 c0 = {0.f,0.f,0.f,0.f}, c1 = {0.f,0.f,0.f,0.f};
        c0 = MFMA32(ka0, qa0, c0);
        c0 = MFMA32(ka1, qa1, c0);
        c1 = MFMA32(kb0, qa0, c1);
        c1 = MFMA32(kb1, qa1, c1);

        const unsigned int blo = bm >> (g * 4);
        const unsigned int bhi = bm >> (g * 4 + 16);
        float e0 = (blo & 1u) ? 0.f : __expf(c0[0] * 0.125f);
        float e1 = (blo & 2u) ? 0.f : __expf(c0[1] * 0.125f);
        float e2 = (blo & 4u) ? 0.f : __expf(c0[2] * 0.125f);
        float e3 = (blo & 8u) ? 0.f : __expf(c0[3] * 0.125f);
        float e4 = (bhi & 1u) ? 0.f : __expf(c1[0] * 0.125f);
        float e5 = (bhi & 2u) ? 0.f : __expf(c1[1] * 0.125f);
        float e6 = (bhi & 4u) ? 0.f : __expf(c1[2] * 0.125f);
        float e7 = (bhi & 8u) ? 0.f : __expf(c1[3] * 0.125f);

        // e packed f16 == PV B-fragment directly (K=16 MFMA), no LDS bounce
        half4 h0 = { (_Float16)e0, (_Float16)e1, (_Float16)e2, (_Float16)e3 };
        half4 h1 = { (_Float16)e4, (_Float16)e5, (_Float16)e6, (_Float16)e7 };
        o0 = MFMA16(va00, h0, o0);
        o0 = MFMA16(va01, h1, o0);
        o1 = MFMA16(va10, h0, o1);
        o1 = MFMA16(va11, h1, o1);
        o2 = MFMA16(va20, h0, o2);
        o2 = MFMA16(va21, h1, o2);
        o3 = MFMA16(va30, h0, o3);
        o3 = MFMA16(va31, h1, o3);

        // attn: normalized fp32 straight from registers, stores last
        floatx4 a0 = { e0 * inv, e1 * inv, e2 * inv, e3 * inv };
        floatx4 a1 = { e4 * inv, e5 * inv, e6 * inv, e7 * inv };
        *(floatx4*)(abase + jj)      = a0;
        *(floatx4*)(abase + jj + 16) = a1;
    }

    // ---- cross-wave reduction of out partials ----
    // o{dt}[i] = out[rl][dt*16 + g*4 + i] (this wave's j-chunks only, unnormalized)
    {
        float* orow = &outred[wave][rl][g * 4];
        *(floatx4*)(orow +  0) = o0;
        *(floatx4*)(orow + 16) = o1;
        *(floatx4*)(orow + 32) = o2;
        *(floatx4*)(orow + 48) = o3;
    }
    __syncthreads();
    {
        const int r  = threadIdx.x >> 4;        // 0..15
        const int c4 = (threadIdx.x & 15) << 2; // 0,4,..,60
        floatx4 s0 = *(const floatx4*)(&outred[0][r][c4]);
        floatx4 s1 = *(const floatx4*)(&outred[1][r][c4]);
        floatx4 s2 = *(const floatx4*)(&outred[2][r][c4]);
        floatx4 s3 = *(const floatx4*)(&outred[3][r][c4]);
        floatx4 s = (s0 + s1) + (s2 + s3);
        const float inv2 = 1.0f / (wsum[0][r] + wsum[1][r] + wsum[2][r] + wsum[3][r]);
        floatx4 ov = { s[0] * inv2, s[1] * inv2, s[2] * inv2, s[3] * inv2 };
        *(floatx4*)(out + ((size_t)(b * SEQ + r0 + r)) * DIM + c4) = ov;
    }
}

extern "C" void kernel_launch(void* const* d_in, const int* in_sizes, int n_in,
                              void* d_out, int out_size, void* d_ws, size_t ws_size,
                              hipStream_t stream) {
    const float* q = (const float*)d_in[0];
    const float* k = (const float*)d_in[1];
    const float* v = (const float*)d_in[2];
    const int* mask = (const int*)d_in[3];   // bool delivered as int32 per harness

    float* out  = (float*)d_out;                       // [16,2048,64]
    float* attn = out + (size_t)NB * SEQ * DIM;        // [16,2048,2048]

    // workspace: qh | kh | vt (f16, 4 MB each) | bits (8 MB) = 20 MB total
    _Float16* qh = (_Float16*)d_ws;
    _Float16* kh = qh + (size_t)NB * SEQ * DIM;
    _Float16* vt = kh + (size_t)NB * SEQ * DIM;
    unsigned int* bits = (unsigned int*)(vt + (size_t)NB * SEQ * DIM);

    cvt_qk_kernel<<<(NB * SEQ * DIM) / 1024, 256, 0, stream>>>(q, k, qh, kh);
    cvt_vt_kernel<<<NB * (SEQ / 64), 256, 0, stream>>>(v, vt);
    mask_bits_kernel<<<(NB * SEQ) / 4, 256, 0, stream>>>(mask, bits);
    attn_kernel<<<NB * (SEQ / 16), 256, 0, stream>>>(qh, kh, vt, bits, out, attn);
}